// Round 7
// baseline (540.123 us; speedup 1.0000x reference)
//
#include <hip/hip_runtime.h>
#include <cstdint>

// Problem constants (from reference): N=8, C=3, H=720, W=1280
constexpr int N_ = 8;
constexpr int C_ = 3;
constexpr int H_ = 720;
constexpr int W_ = 1280;
constexpr int HW = H_ * W_;

typedef float vf4 __attribute__((ext_vector_type(4)));

// key = (bits(v) << 32) | (p+1);  v = fx*fx+fy*fy >= 0 so IEEE bits preserve
// order; low 32 bits implement "larger source index wins ties" (reference's
// stable ascending argsort -> max rank wins). key==0 <=> hole.
__device__ __forceinline__ unsigned long long make_key(float fx, float fy, int p) {
    // exact mul-mul-add in fp32, no FMA contraction (must match numpy bits)
    float v = __fadd_rn(__fmul_rn(fx, fx), __fmul_rn(fy, fy));
    return ((unsigned long long)__float_as_uint(v) << 32) | (unsigned int)(p + 1);
}

// ======================= Path A: global scatter =======================
// Keys array (59MB) fits the 256MB memory-side L3: the 7.4M no-return
// u64 atomicMax RMWs resolve in LLC, spread over 920K lines (~8/line —
// R1's serialization was 20K atomics on ONE line). Flow is read exactly
// once (kills the tile path's 6x overscan), no LDS, no barriers, no
// outlier pass, no tile tail.
constexpr int SBLK = 1024;
constexpr int CHUNK = SBLK * 4;              // 4096 px per block
constexpr int NCHUNK = HW / CHUNK;           // 225 exactly (225*4096 = HW)

__global__ __launch_bounds__(SBLK) void scatter_kernel(
    const float* __restrict__ flow,
    unsigned long long* __restrict__ keys) {
    int n     = blockIdx.x & 7;              // N_ == 8
    int chunk = blockIdx.x >> 3;             // 0..224
    int p0 = chunk * CHUNK + (int)threadIdx.x * 4;
    const float* f = flow + (size_t)n * 2 * HW;
    vf4 fx4 = *(const vf4*)(f + p0);
    vf4 fy4 = *(const vf4*)(f + HW + p0);
    unsigned long long* kb = keys + (size_t)n * HW;
    int y  = p0 / W_;                        // const divisor: magic-mul
    int x0 = p0 - y * W_;                    // p0 mult of 4, W%4==0: same row
    float fxs[4] = {fx4.x, fx4.y, fx4.z, fx4.w};
    float fys[4] = {fy4.x, fy4.y, fy4.z, fy4.w};
    #pragma unroll
    for (int i = 0; i < 4; ++i) {
        int wx = min(max(x0 + i + (int)fxs[i], 0), W_ - 1);  // trunc == astype(i32)
        int wy = min(max(y + (int)fys[i], 0), H_ - 1);
        atomicMax(&kb[wy * W_ + wx], make_key(fxs[i], fys[i], p0 + i));
    }
}

__global__ __launch_bounds__(SBLK) void gather_kernel(
    const float* __restrict__ image,
    const unsigned long long* __restrict__ keys,
    float* __restrict__ out) {
    int n     = blockIdx.x & 7;
    int chunk = blockIdx.x >> 3;
    int p0 = chunk * CHUNK + (int)threadIdx.x * 4;
    const unsigned long long* kb = keys + (size_t)n * HW + p0;
    ulonglong2 ka = *(const ulonglong2*)(kb);        // 32B/lane coalesced
    ulonglong2 kc = *(const ulonglong2*)(kb + 2);
    unsigned long long k0 = ka.x, k1 = ka.y, k2 = kc.x, k3 = kc.y;
    int s0 = (int)(unsigned int)(k0 & 0xffffffffULL) - 1;
    int s1 = (int)(unsigned int)(k1 & 0xffffffffULL) - 1;
    int s2 = (int)(unsigned int)(k2 & 0xffffffffULL) - 1;
    int s3 = (int)(unsigned int)(k3 & 0xffffffffULL) - 1;
    const float* img_n = image + (size_t)n * C_ * HW;
    float* out_n = out + (size_t)n * C_ * HW + p0;
    #pragma unroll
    for (int c = 0; c < C_; ++c) {
        const float* pl = img_n + (size_t)c * HW;
        vf4 o;                                   // hole lanes exec-masked off loads
        o.x = k0 ? pl[s0] : 0.0f;
        o.y = k1 ? pl[s1] : 0.0f;
        o.z = k2 ? pl[s2] : 0.0f;
        o.w = k3 ? pl[s3] : 0.0f;
        __builtin_nontemporal_store(o, (vf4*)(out_n + (size_t)c * HW));
    }
}

// ============== Path B: R6 tile fallback (small workspace) ==============
constexpr int TW = 128;
constexpr int TH = 64;
constexpr int M_ = 64;
constexpr int NTX = W_ / TW;                 // 10
constexpr int NTY = (H_ + TH - 1) / TH;      // 12
constexpr int BLK = 1024;
constexpr int OSEG = 16384;
constexpr int SCAP = 128;
constexpr int CSTRIDE = 16;
constexpr int BPB = HW / 1024;               // 900
constexpr int NSWEEP = (TH + 2 * M_) / (BLK / 64);   // 12

struct Outlier { unsigned long long key; int tgt; int pad; };  // 16 B

__global__ __launch_bounds__(256) void outlier_kernel(
    const float* __restrict__ flow,
    unsigned long long* __restrict__ ocnt,
    Outlier* __restrict__ olist) {
    __shared__ unsigned int bcnt;
    __shared__ unsigned long long gbase;
    __shared__ unsigned long long skey[SCAP];
    __shared__ int stgt[SCAP];
    if (threadIdx.x == 0) bcnt = 0;
    __syncthreads();

    int n  = blockIdx.x / BPB;
    int p0 = (blockIdx.x - n * BPB) * 1024 + threadIdx.x * 4;
    const float* f = flow + (size_t)n * 2 * HW;
    vf4 fx4 = *(const vf4*)(f + p0);
    vf4 fy4 = *(const vf4*)(f + HW + p0);
    float fxs[4] = {fx4.x, fx4.y, fx4.z, fx4.w};
    float fys[4] = {fy4.x, fy4.y, fy4.z, fy4.w};
    int y = p0 / W_;
    int x0 = p0 - y * W_;
    #pragma unroll
    for (int i = 0; i < 4; ++i) {
        int dx = (int)fxs[i];
        int dy = (int)fys[i];
        if (dx > M_ || dx < -M_ || dy > M_ || dy < -M_) {
            int wx = min(max(x0 + i + dx, 0), W_ - 1);
            int wy = min(max(y + dy, 0), H_ - 1);
            unsigned long long key = make_key(fxs[i], fys[i], p0 + i);
            int tgt = wy * W_ + wx;
            unsigned int s = atomicAdd(&bcnt, 1u);
            if (s < (unsigned)SCAP) {
                skey[s] = key; stgt[s] = tgt;
            } else {
                unsigned long long o = atomicAdd(&ocnt[(size_t)n * CSTRIDE], 1ULL);
                if (o < (unsigned long long)OSEG) {
                    Outlier e; e.key = key; e.tgt = tgt; e.pad = 0;
                    olist[n * OSEG + (int)o] = e;
                }
            }
        }
    }
    __syncthreads();
    unsigned int c = bcnt > (unsigned)SCAP ? (unsigned)SCAP : bcnt;
    if (threadIdx.x == 0)
        gbase = c ? atomicAdd(&ocnt[(size_t)n * CSTRIDE], (unsigned long long)c)
                  : 0ULL;
    __syncthreads();
    for (unsigned int i = threadIdx.x; i < c; i += 256) {
        unsigned long long o = gbase + i;
        if (o < (unsigned long long)OSEG) {
            Outlier e; e.key = skey[i]; e.tgt = stgt[i]; e.pad = 0;
            olist[n * OSEG + (int)o] = e;
        }
    }
}

__global__ __launch_bounds__(BLK, 8) void warp_tile_kernel(
    const float* __restrict__ image,
    const float* __restrict__ flow,
    const unsigned long long* __restrict__ ocnt,
    const Outlier* __restrict__ olist,
    float* __restrict__ out) {
    __shared__ unsigned long long lkey[TH * TW];          // 64 KB
    int bid = blockIdx.x;
    int n    = bid & 7;
    int tile = bid >> 3;
    int tyi = tile / NTX;
    int txi = tile - tyi * NTX;
    int tx0 = txi * TW;
    int ty0 = tyi * TH;
    int th_eff = min(TH, H_ - ty0);
    int tid = threadIdx.x;

    {
        ulonglong2 z; z.x = 0ULL; z.y = 0ULL;
        ulonglong2* l2p = (ulonglong2*)lkey;
        #pragma unroll
        for (int i = 0; i < (TH * TW) / 2 / BLK; ++i)
            l2p[tid + i * BLK] = z;
    }
    __syncthreads();

    {
        unsigned long long craw = ocnt[(size_t)n * CSTRIDE];
        int cnt = (int)(craw > (unsigned long long)OSEG ? OSEG : craw);
        const Outlier* seg = olist + n * OSEG;
        for (int o = tid; o < cnt; o += BLK) {
            Outlier e = seg[o];
            int ey = e.tgt / W_, ex = e.tgt - ey * W_;
            int lx = ex - tx0, ly = ey - ty0;
            if ((unsigned)lx < (unsigned)TW && (unsigned)ly < (unsigned)th_eff)
                atomicMax(&lkey[ly * TW + lx], e.key);
        }
    }

    const float* fx_p = flow + (size_t)n * 2 * HW;
    const float* fy_p = fx_p + HW;
    int x4   = tx0 - M_ + ((tid & 63) << 2);
    int yv0  = ty0 - M_ + (tid >> 6);
    bool xok = (unsigned)x4 < (unsigned)W_;
    #pragma unroll 4
    for (int s = 0; s < NSWEEP; ++s) {
        int y = yv0 + s * 16;
        if (xok && (unsigned)y < (unsigned)H_) {
            int pbase = y * W_ + x4;
            vf4 fx4 = *(const vf4*)(fx_p + pbase);
            vf4 fy4 = *(const vf4*)(fy_p + pbase);
            float fxs[4] = {fx4.x, fx4.y, fx4.z, fx4.w};
            float fys[4] = {fy4.x, fy4.y, fy4.z, fy4.w};
            #pragma unroll
            for (int i = 0; i < 4; ++i) {
                float fx = fxs[i], fy = fys[i];
                int wx = x4 + i + (int)fx;
                int wy = y + (int)fy;
                wx = min(max(wx, 0), W_ - 1);
                wy = min(max(wy, 0), H_ - 1);
                int lx = wx - tx0, ly = wy - ty0;
                if ((unsigned)lx < (unsigned)TW && (unsigned)ly < (unsigned)th_eff) {
                    atomicMax(&lkey[ly * TW + lx], make_key(fx, fy, pbase + i));
                }
            }
        }
    }
    __syncthreads();

    const float* img_n = image + (size_t)n * C_ * HW;
    float* out_n = out + (size_t)n * C_ * HW;
    int q4 = th_eff * (TW / 4);
    for (int s = tid; s < q4; s += BLK) {
        int r = s >> 5;
        int cg = s & 31;
        int lp = r * TW + cg * 4;
        unsigned long long k0 = lkey[lp],     k1 = lkey[lp + 1];
        unsigned long long k2 = lkey[lp + 2], k3 = lkey[lp + 3];
        int s0 = (int)(unsigned int)(k0 & 0xffffffffULL) - 1;
        int s1 = (int)(unsigned int)(k1 & 0xffffffffULL) - 1;
        int s2 = (int)(unsigned int)(k2 & 0xffffffffULL) - 1;
        int s3 = (int)(unsigned int)(k3 & 0xffffffffULL) - 1;
        int op = (ty0 + r) * W_ + tx0 + cg * 4;
        #pragma unroll
        for (int c = 0; c < C_; ++c) {
            const float* pl = img_n + (size_t)c * HW;
            vf4 o;
            o.x = k0 ? pl[s0] : 0.0f;
            o.y = k1 ? pl[s1] : 0.0f;
            o.z = k2 ? pl[s2] : 0.0f;
            o.w = k3 ? pl[s3] : 0.0f;
            __builtin_nontemporal_store(o, (vf4*)(out_n + (size_t)c * HW + op));
        }
    }
}

extern "C" void kernel_launch(void* const* d_in, const int* in_sizes, int n_in,
                              void* d_out, int out_size, void* d_ws, size_t ws_size,
                              hipStream_t stream) {
    const float* image = (const float*)d_in[0];
    const float* flow  = (const float*)d_in[1];
    float* out = (float*)d_out;

    size_t keys_bytes = (size_t)N_ * HW * 8;               // 59 MB
    if (ws_size >= keys_bytes) {
        // Path A: global scatter (keys fit L3; atomics spread over 920K lines)
        unsigned long long* keys = (unsigned long long*)d_ws;
        (void)hipMemsetAsync(keys, 0, keys_bytes, stream);
        scatter_kernel<<<N_ * NCHUNK, SBLK, 0, stream>>>(flow, keys);
        gather_kernel<<<N_ * NCHUNK, SBLK, 0, stream>>>(image, keys, out);
    } else {
        // Path B: proven R6 tile path (needs ~2MB workspace)
        unsigned long long* ocnt = (unsigned long long*)d_ws;
        Outlier* olist = (Outlier*)((char*)d_ws + 1024);
        (void)hipMemsetAsync(ocnt, 0, 1024, stream);
        int k0_blocks = (N_ * HW / 4) / 256;               // 7200
        outlier_kernel<<<k0_blocks, 256, 0, stream>>>(flow, ocnt, olist);
        warp_tile_kernel<<<N_ * NTX * NTY, BLK, 0, stream>>>(
            image, flow, ocnt, olist, out);
    }
}